// Round 7
// baseline (115.994 us; speedup 1.0000x reference)
//
#include <hip/hip_runtime.h>

// InversePreEmphasis: h_t = tanh(x_t + 0.97*h_{t-1}) along T, per row.
// Chunked-parallel with warm-up (per-step contraction 0.97*(1-h^2)).
// R7: no inline-asm loads (R4-R6's "memory"-clobbered asm pushed the load
// buffers into scratch: VGPR=40, WRITE_SIZE 322MB = output + spill).
// Plain float4 loads into NAMED locals, pinned early with
// sched_barrier(0); compiler emits its own counted vmcnt before uses.

constexpr int Bn = 256;
constexpr int T  = 131072;
constexpr int S  = 64;         // outputs per thread (16 float4)
constexpr int C  = T / S;      // 2048 chunks per row
constexpr int W  = 32;         // warm-up steps (8 float4)

// tanh(x + 0.97h) = 1 - 2*rcp(exp2(g*x + 0.97*g*h) + 1),  g = 2*log2(e)
// state r: h = 1-2r;  t = fma(N2CG, r, fma(GLN, x, CGLN))
constexpr float GLN  = 2.885390081777927f;          // 2*log2(e)
constexpr float CGLN = 0.97f * 2.885390081777927f;
constexpr float N2CG = -2.0f * 0.97f * 2.885390081777927f;

__device__ __forceinline__ float step1(float& r, float xin) {
    float t = fmaf(N2CG, r, fmaf(GLN, xin, CGLN));   // inner fmaf off-chain
    float e = __builtin_amdgcn_exp2f(t);
    r = __builtin_amdgcn_rcpf(e + 1.0f);
    return fmaf(-2.0f, r, 1.0f);
}

__device__ __forceinline__ float4 step4(float& r, float4 v) {
    float4 o;
    o.x = step1(r, v.x);
    o.y = step1(r, v.y);
    o.z = step1(r, v.z);
    o.w = step1(r, v.w);
    return o;
}

__global__ __launch_bounds__(256, 5) void ipe_scan_kernel(const float* __restrict__ x,
                                                          float* __restrict__ y) {
    const int tid = blockIdx.x * blockDim.x + threadIdx.x;
    const int b = tid / C;
    const int c = tid % C;
    const float* xr = x + (size_t)b * T;
    const int start = c * S;

    // c==0: dummy warm-up over x[0..W) (valid memory), state reset below.
    const float4* pw4 = reinterpret_cast<const float4*>(xr + (start >= W ? start - W : 0));
    const float4* pb4 = reinterpret_cast<const float4*>(xr + start);
    float4*       po4 = reinterpret_cast<float4*>(y + (size_t)b * T + start);

    // ---- issue warm-up (8) + body-A (8) loads, pinned before any compute ----
    float4 w0 = pw4[0], w1 = pw4[1], w2 = pw4[2], w3 = pw4[3];
    float4 w4 = pw4[4], w5 = pw4[5], w6 = pw4[6], w7 = pw4[7];
    float4 a0 = pb4[0], a1 = pb4[1], a2 = pb4[2], a3 = pb4[3];
    float4 a4 = pb4[4], a5 = pb4[5], a6 = pb4[6], a7 = pb4[7];
    __builtin_amdgcn_sched_barrier(0);   // nothing crosses: all 16 loads issued

    float r = 0.5f;         // h = 1 - 2r = 0

    // ---- warm-up chain (outputs dead -> compiler drops the h-fmaf) ----
    (void)step4(r, w0); (void)step4(r, w1); (void)step4(r, w2); (void)step4(r, w3);
    (void)step4(r, w4); (void)step4(r, w5); (void)step4(r, w6); (void)step4(r, w7);

    if (c == 0) r = 0.5f;   // exact h0 = 0 for the first chunk

    // ---- issue body-B loads before consuming A ----
    float4 b0 = pb4[8],  b1 = pb4[9],  b2 = pb4[10], b3 = pb4[11];
    float4 b4 = pb4[12], b5 = pb4[13], b6 = pb4[14], b7 = pb4[15];
    __builtin_amdgcn_sched_barrier(0);   // B loads issued before A-chain

    // ---- body: chain + store ----
    po4[0] = step4(r, a0); po4[1] = step4(r, a1);
    po4[2] = step4(r, a2); po4[3] = step4(r, a3);
    po4[4] = step4(r, a4); po4[5] = step4(r, a5);
    po4[6] = step4(r, a6); po4[7] = step4(r, a7);

    po4[8]  = step4(r, b0); po4[9]  = step4(r, b1);
    po4[10] = step4(r, b2); po4[11] = step4(r, b3);
    po4[12] = step4(r, b4); po4[13] = step4(r, b5);
    po4[14] = step4(r, b6); po4[15] = step4(r, b7);
}

extern "C" void kernel_launch(void* const* d_in, const int* in_sizes, int n_in,
                              void* d_out, int out_size, void* d_ws, size_t ws_size,
                              hipStream_t stream) {
    const float* x = (const float*)d_in[0];
    float*       y = (float*)d_out;
    const int total_threads = Bn * C;          // 524288
    const int block = 256;
    const int grid = total_threads / block;    // 2048
    ipe_scan_kernel<<<grid, block, 0, stream>>>(x, y);
}

// Round 8
// 97.982 us; speedup vs baseline: 1.1838x; 1.1838x over previous
//
#include <hip/hip_runtime.h>

// InversePreEmphasis: h_t = tanh(x_t + 0.97*h_{t-1}) along T, per row.
// Chunked-parallel with warm-up (per-step contraction 0.97*(1-h^2)).
// R8: R7 structure + amdgpu_waves_per_eu(4,4). R4-R7 all spilled the
// prefetch buffers to scratch (VGPR=40 < 64 live, WRITE_SIZE 2.4x output):
// the GCN scheduler chases the 8-waves/EU tier (<=64 VGPR) because
// launch_bounds' 2nd arg is only a MINIMUM. Pinning waves_per_eu at
// exactly 4 gives a 128-VGPR budget -> buffers stay in registers.

constexpr int Bn = 256;
constexpr int T  = 131072;
constexpr int S  = 64;         // outputs per thread (16 float4)
constexpr int C  = T / S;      // 2048 chunks per row
constexpr int W  = 32;         // warm-up steps (8 float4)

// tanh(x + 0.97h) = 1 - 2*rcp(exp2(g*x + 0.97*g*h) + 1),  g = 2*log2(e)
// state r: h = 1-2r;  t = fma(N2CG, r, fma(GLN, x, CGLN))
constexpr float GLN  = 2.885390081777927f;          // 2*log2(e)
constexpr float CGLN = 0.97f * 2.885390081777927f;
constexpr float N2CG = -2.0f * 0.97f * 2.885390081777927f;

__device__ __forceinline__ float step1(float& r, float xin) {
    float t = fmaf(N2CG, r, fmaf(GLN, xin, CGLN));   // inner fmaf off-chain
    float e = __builtin_amdgcn_exp2f(t);
    r = __builtin_amdgcn_rcpf(e + 1.0f);
    return fmaf(-2.0f, r, 1.0f);
}

__device__ __forceinline__ float4 step4(float& r, float4 v) {
    float4 o;
    o.x = step1(r, v.x);
    o.y = step1(r, v.y);
    o.z = step1(r, v.z);
    o.w = step1(r, v.w);
    return o;
}

__global__ __launch_bounds__(256)
__attribute__((amdgpu_waves_per_eu(4, 4)))
void ipe_scan_kernel(const float* __restrict__ x, float* __restrict__ y) {
    const int tid = blockIdx.x * blockDim.x + threadIdx.x;
    const int b = tid / C;
    const int c = tid % C;
    const float* xr = x + (size_t)b * T;
    const int start = c * S;

    // c==0: dummy warm-up over x[0..W) (valid memory), state reset below.
    const float4* pw4 = reinterpret_cast<const float4*>(xr + (start >= W ? start - W : 0));
    const float4* pb4 = reinterpret_cast<const float4*>(xr + start);
    float4*       po4 = reinterpret_cast<float4*>(y + (size_t)b * T + start);

    // ---- issue warm-up (8) + body-A (8) loads, pinned before any compute ----
    float4 w0 = pw4[0], w1 = pw4[1], w2 = pw4[2], w3 = pw4[3];
    float4 w4 = pw4[4], w5 = pw4[5], w6 = pw4[6], w7 = pw4[7];
    float4 a0 = pb4[0], a1 = pb4[1], a2 = pb4[2], a3 = pb4[3];
    float4 a4 = pb4[4], a5 = pb4[5], a6 = pb4[6], a7 = pb4[7];
    __builtin_amdgcn_sched_barrier(0);   // all 16 loads issued before compute

    float r = 0.5f;         // h = 1 - 2r = 0

    // ---- warm-up chain (outputs dead) ----
    (void)step4(r, w0); (void)step4(r, w1); (void)step4(r, w2); (void)step4(r, w3);
    (void)step4(r, w4); (void)step4(r, w5); (void)step4(r, w6); (void)step4(r, w7);

    if (c == 0) r = 0.5f;   // exact h0 = 0 for the first chunk

    // ---- issue body-B loads before consuming A ----
    float4 b0 = pb4[8],  b1 = pb4[9],  b2 = pb4[10], b3 = pb4[11];
    float4 b4 = pb4[12], b5 = pb4[13], b6 = pb4[14], b7 = pb4[15];
    __builtin_amdgcn_sched_barrier(0);   // B loads issued before A-chain

    // ---- body: chain + store ----
    po4[0] = step4(r, a0); po4[1] = step4(r, a1);
    po4[2] = step4(r, a2); po4[3] = step4(r, a3);
    po4[4] = step4(r, a4); po4[5] = step4(r, a5);
    po4[6] = step4(r, a6); po4[7] = step4(r, a7);

    po4[8]  = step4(r, b0); po4[9]  = step4(r, b1);
    po4[10] = step4(r, b2); po4[11] = step4(r, b3);
    po4[12] = step4(r, b4); po4[13] = step4(r, b5);
    po4[14] = step4(r, b6); po4[15] = step4(r, b7);
}

extern "C" void kernel_launch(void* const* d_in, const int* in_sizes, int n_in,
                              void* d_out, int out_size, void* d_ws, size_t ws_size,
                              hipStream_t stream) {
    const float* x = (const float*)d_in[0];
    float*       y = (float*)d_out;
    const int total_threads = Bn * C;          // 524288
    const int block = 256;
    const int grid = total_threads / block;    // 2048
    ipe_scan_kernel<<<grid, block, 0, stream>>>(x, y);
}